// Round 8
// baseline (53.625 us; speedup 1.0000x reference)
//
#include <hip/hip_runtime.h>

#define BSZ 8192
#define DIM 128
#define NLAB 1024
#define MARGIN 0.3f
#define EPS 1e-8f
#define NJ 32              // j-splits
#define JCHUNK 256         // BSZ / NJ
#define NPH 8              // phases per block (32 cols each)

typedef __bf16 bf16x8 __attribute__((ext_vector_type(8)));
typedef float f32x4 __attribute__((ext_vector_type(4)));

#define AS1 __attribute__((address_space(1)))
#define AS3 __attribute__((address_space(3)))

// order-preserving float <-> uint key
__device__ __forceinline__ unsigned enc_ord(float f) {
    unsigned u = __float_as_uint(f);
    return (u & 0x80000000u) ? ~u : (u | 0x80000000u);
}
__device__ __forceinline__ float dec_ord(unsigned e) {
    unsigned u = (e & 0x80000000u) ? (e & 0x7FFFFFFFu) : ~e;
    return __uint_as_float(u);
}

template <int N>
__device__ __forceinline__ void waitv() {
    if constexpr (N == 4) asm volatile("s_waitcnt vmcnt(4)" ::: "memory");
    else if constexpr (N == 2) asm volatile("s_waitcnt vmcnt(2)" ::: "memory");
    else asm volatile("s_waitcnt vmcnt(0)" ::: "memory");
}

// ---- sort by label: histogram + scan (1 block), then scatter ----
__global__ __launch_bounds__(1024) void k_sort(const int* __restrict__ labels,
                                               unsigned* __restrict__ start,
                                               unsigned* __restrict__ offset) {
    __shared__ unsigned h[NLAB];
    const int tid = threadIdx.x;
    h[tid] = 0u;
    __syncthreads();
#pragma unroll
    for (int s = 0; s < BSZ / NLAB; ++s)
        atomicAdd(&h[labels[s * NLAB + tid]], 1u);
    __syncthreads();
    // inclusive scan (Hillis-Steele)
    for (int d = 1; d < NLAB; d <<= 1) {
        unsigned w = (tid >= d) ? h[tid - d] : 0u;
        __syncthreads();
        h[tid] += w;
        __syncthreads();
    }
    start[tid + 1] = h[tid];
    if (tid == 0) start[0] = 0u;
    offset[tid] = (tid > 0) ? h[tid - 1] : 0u;
}

__global__ __launch_bounds__(256) void k_scatter(const int* __restrict__ labels,
                                                 unsigned* __restrict__ offset,
                                                 int* __restrict__ perm,
                                                 int* __restrict__ slab) {
    int i = blockIdx.x * 256 + threadIdx.x;
    int lab = labels[i];
    unsigned pos = atomicAdd(&offset[lab], 1u);
    perm[pos] = i;
    slab[pos] = lab;
}

// gather rows into label-sorted order, convert to bf16, row norms, init reductions
__global__ __launch_bounds__(256) void k_prep(const float* __restrict__ emb,
                                              const int* __restrict__ perm,
                                              __bf16* __restrict__ hi,
                                              float* __restrict__ sq,
                                              unsigned* __restrict__ maxp,
                                              unsigned* __restrict__ minn,
                                              float* __restrict__ sumcnt) {
    int row = blockIdx.x * 4 + (threadIdx.x >> 6);
    int lane = threadIdx.x & 63;
    int src = perm[row];
    float2 v = *(const float2*)&emb[(size_t)src * DIM + lane * 2];
    union { __bf16 b[2]; unsigned u; } p;
    p.b[0] = (__bf16)v.x;
    p.b[1] = (__bf16)v.y;
    ((unsigned*)hi)[row * 64 + lane] = p.u;
    float s = v.x * v.x + v.y * v.y;
#pragma unroll
    for (int m = 32; m >= 1; m >>= 1) s += __shfl_xor(s, m);
    if (lane == 0) {
        sq[row] = s;
        maxp[row] = 0u;
        minn[row] = 0xFFFFFFFFu;
    }
    if (blockIdx.x == 0 && threadIdx.x == 0) {
        sumcnt[0] = 0.0f;
        ((unsigned*)sumcnt)[1] = 0u;
    }
}

// 4 waves, 128 sorted anchor rows, 32-col phases, 4-deep LDS ring,
// depth-2 prefetch, counted vmcnt + raw s_barrier (no full drain in loop).
// Sorted labels => per-block positive band => ~94% negative-only phases.
__global__ __launch_bounds__(256, 4) void k_mfma(const __bf16* __restrict__ hi,
                                                 const int* __restrict__ slab,
                                                 const unsigned* __restrict__ startp,
                                                 const float* __restrict__ sq,
                                                 unsigned* __restrict__ maxp,
                                                 unsigned* __restrict__ minn) {
    __shared__ char Bst[4][8][1024];   // [ring buf][frag m][lane*16B]
    __shared__ float sqlds[JCHUNK];
    __shared__ int lablds[JCHUNK];

    const int tid = threadIdx.x;
    const int lane = tid & 63;
    const int wave = tid >> 6;
    const int lr = lane & 15;
    const int lq = lane >> 4;
    const int i0 = blockIdx.x * 128;
    const int it0 = i0 + wave * 32;
    const int it1 = it0 + 16;
    const int j0 = blockIdx.y * JCHUNK;
    const float INF = __uint_as_float(0x7F800000u);

    // positive band of this block's anchors (sorted rows => contiguous labels)
    const int lf = slab[i0];
    const int ll = slab[i0 + 127];
    const int blo = (int)startp[lf];
    const int bhi = (int)startp[ll + 1];
    unsigned mmask = 0;
#pragma unroll
    for (int tt = 0; tt < NPH; ++tt) {
        int c0 = j0 + tt * 32;
        if (bhi > c0 && blo < c0 + 32) mmask |= (1u << tt);
    }

    sqlds[tid] = sq[j0 + tid];
    lablds[tid] = slab[j0 + tid];

    // A fragments: 2 i-tiles x 4 K-frags, register-resident, pinned
    bf16x8 a0[4], a1[4];
    const __bf16* ap = hi + (size_t)(it0 + lr) * DIM + lq * 8;
#pragma unroll
    for (int f = 0; f < 4; ++f) {
        a0[f] = *(const bf16x8*)&ap[f * 32];
        a1[f] = *(const bf16x8*)&ap[16 * DIM + f * 32];
        asm volatile("" : "+v"(a0[f]));
        asm volatile("" : "+v"(a1[f]));
    }
    const int4 li0 = *(const int4*)&slab[it0 + lq * 4];
    const int4 li1 = *(const int4*)&slab[it1 + lq * 4];
    const int labi0[4] = {li0.x, li0.y, li0.z, li0.w};
    const int labi1[4] = {li1.x, li1.y, li1.z, li1.w};

    float mp0[4], mp1[4], mn0[4], mn1[4];
#pragma unroll
    for (int r = 0; r < 4; ++r) {
        mp0[r] = -INF; mp1[r] = -INF;
        mn0[r] = INF;  mn1[r] = INF;
    }

    // wave w stages frags m0=2w, m1=2w+1 (frag m: j-subtile m>>2, K-frag m&3)
    const int m0 = wave * 2, m1 = m0 + 1;
    const __bf16* bsA = hi + (size_t)(j0 + (m0 >> 2) * 16 + lr) * DIM + (m0 & 3) * 32 + lq * 8;
    const __bf16* bsB = hi + (size_t)(j0 + (m1 >> 2) * 16 + lr) * DIM + (m1 & 3) * 32 + lq * 8;
#define STAGE(t, buf)                                                              \
    do {                                                                           \
        __builtin_amdgcn_global_load_lds(                                          \
            (const AS1 void*)(bsA + (size_t)(t) * 32 * DIM),                       \
            (AS3 void*)&Bst[buf][m0][0], 16, 0, 0);                                \
        __builtin_amdgcn_global_load_lds(                                          \
            (const AS1 void*)(bsB + (size_t)(t) * 32 * DIM),                       \
            (AS3 void*)&Bst[buf][m1][0], 16, 0, 0);                                \
    } while (0)

    STAGE(0, 0);
    STAGE(1, 1);
    __syncthreads();   // full drain: bufs 0,1 resident; sqlds/lablds visible

#pragma unroll 1
    for (int t = 0; t < NPH; ++t) {
        if (t + 2 < NPH) STAGE(t + 2, (t + 2) & 3);
        if (t < NPH - 2) waitv<4>();         // retire phase-t loads (wave-local)
        else if (t == NPH - 2) waitv<2>();
        else waitv<0>();
        __builtin_amdgcn_s_barrier();        // all waves' phase-t frags resident
        __builtin_amdgcn_sched_barrier(0);   // pin ds_reads below the barrier

        const float sqj0 = sqlds[t * 32 + lr];
        const float sqj1 = sqlds[t * 32 + 16 + lr];

        const bf16x8* bp = (const bf16x8*)&Bst[t & 3][0][0];
        f32x4 acc00 = {0, 0, 0, 0}, acc01 = {0, 0, 0, 0};
        f32x4 acc10 = {0, 0, 0, 0}, acc11 = {0, 0, 0, 0};
#pragma unroll
        for (int f = 0; f < 4; ++f) {
            bf16x8 b0 = bp[f * 64 + lane];
            bf16x8 b1 = bp[(4 + f) * 64 + lane];
            acc00 = __builtin_amdgcn_mfma_f32_16x16x32_bf16(a0[f], b0, acc00, 0, 0, 0);
            acc10 = __builtin_amdgcn_mfma_f32_16x16x32_bf16(a1[f], b0, acc10, 0, 0, 0);
            acc01 = __builtin_amdgcn_mfma_f32_16x16x32_bf16(a0[f], b1, acc01, 0, 0, 0);
            acc11 = __builtin_amdgcn_mfma_f32_16x16x32_bf16(a1[f], b1, acc11, 0, 0, 0);
        }

        if (mmask & (1u << t)) {   // mixed phase: full label-aware epilogue
            const int labj0 = lablds[t * 32 + lr];
            const int labj1 = lablds[t * 32 + 16 + lr];
#pragma unroll
            for (int r = 0; r < 4; ++r) {
                float k00 = fmaf(-2.0f, acc00[r], sqj0);
                float k01 = fmaf(-2.0f, acc01[r], sqj1);
                float k10 = fmaf(-2.0f, acc10[r], sqj0);
                float k11 = fmaf(-2.0f, acc11[r], sqj1);
                bool s00 = (labj0 == labi0[r]);
                bool s01 = (labj1 == labi0[r]);
                bool s10 = (labj0 == labi1[r]);
                bool s11 = (labj1 == labi1[r]);
                mp0[r] = s00 ? fmaxf(mp0[r], k00) : mp0[r];
                mn0[r] = s00 ? mn0[r] : fminf(mn0[r], k00);
                mp0[r] = s01 ? fmaxf(mp0[r], k01) : mp0[r];
                mn0[r] = s01 ? mn0[r] : fminf(mn0[r], k01);
                mp1[r] = s10 ? fmaxf(mp1[r], k10) : mp1[r];
                mn1[r] = s10 ? mn1[r] : fminf(mn1[r], k10);
                mp1[r] = s11 ? fmaxf(mp1[r], k11) : mp1[r];
                mn1[r] = s11 ? mn1[r] : fminf(mn1[r], k11);
            }
        } else {   // pure-negative phase: fmaf + fmin tree only
#pragma unroll
            for (int r = 0; r < 4; ++r) {
                float k00 = fmaf(-2.0f, acc00[r], sqj0);
                float k01 = fmaf(-2.0f, acc01[r], sqj1);
                float k10 = fmaf(-2.0f, acc10[r], sqj0);
                float k11 = fmaf(-2.0f, acc11[r], sqj1);
                mn0[r] = fminf(fminf(mn0[r], k00), k01);
                mn1[r] = fminf(fminf(mn1[r], k10), k11);
            }
        }
    }
#undef STAGE

#pragma unroll
    for (int m = 1; m < 16; m <<= 1) {
#pragma unroll
        for (int r = 0; r < 4; ++r) {
            mp0[r] = fmaxf(mp0[r], __shfl_xor(mp0[r], m));
            mn0[r] = fminf(mn0[r], __shfl_xor(mn0[r], m));
            mp1[r] = fmaxf(mp1[r], __shfl_xor(mp1[r], m));
            mn1[r] = fminf(mn1[r], __shfl_xor(mn1[r], m));
        }
    }
    if (lr == 0) {
#pragma unroll
        for (int r = 0; r < 4; ++r) {
            atomicMax(&maxp[it0 + lq * 4 + r], enc_ord(mp0[r]));
            atomicMin(&minn[it0 + lq * 4 + r], enc_ord(mn0[r]));
            atomicMax(&maxp[it1 + lq * 4 + r], enc_ord(mp1[r]));
            atomicMin(&minn[it1 + lq * 4 + r], enc_ord(mn1[r]));
        }
    }
}

__global__ __launch_bounds__(256) void k_final(const unsigned* __restrict__ maxp,
                                               const unsigned* __restrict__ minn,
                                               const float* __restrict__ sq,
                                               float* __restrict__ sumcnt) {
    int i = blockIdx.x * 256 + threadIdx.x;
    float mpd = dec_ord(maxp[i]);
    float mnd = dec_ord(minn[i]);
    float sqi = sq[i];
    bool valid = (mpd > -1e30f) && (mnd < 1e30f);
    float hp = sqrtf(fmaxf(sqi + mpd, 0.0f) + EPS);
    float hn = sqrtf(fmaxf(sqi + mnd, 0.0f) + EPS);
    float per = valid ? fmaxf(hp - hn + MARGIN, 0.0f) : 0.0f;
    unsigned cnt = valid ? 1u : 0u;
#pragma unroll
    for (int m = 32; m >= 1; m >>= 1) {
        per += __shfl_xor(per, m);
        cnt += __shfl_xor(cnt, m);
    }
    __shared__ float ssum[4];
    __shared__ unsigned scnt[4];
    int wid = threadIdx.x >> 6;
    if ((threadIdx.x & 63) == 0) { ssum[wid] = per; scnt[wid] = cnt; }
    __syncthreads();
    if (threadIdx.x == 0) {
        float s = ssum[0] + ssum[1] + ssum[2] + ssum[3];
        unsigned c = scnt[0] + scnt[1] + scnt[2] + scnt[3];
        atomicAdd(&sumcnt[0], s);
        atomicAdd((unsigned*)&sumcnt[1], c);
    }
}

__global__ void k_out(const float* __restrict__ sumcnt, float* __restrict__ out) {
    if (threadIdx.x == 0) {
        float s = sumcnt[0];
        unsigned c = ((const unsigned*)sumcnt)[1];
        out[0] = s / (float)(c > 0u ? c : 1u);
    }
}

extern "C" void kernel_launch(void* const* d_in, const int* in_sizes, int n_in,
                              void* d_out, int out_size, void* d_ws, size_t ws_size,
                              hipStream_t stream) {
    const float* emb    = (const float*)d_in[0];
    const int*   labels = (const int*)d_in[1];

    // 4-byte-slot layout. hi = 8192*128 bf16 = 2 MB = 524288 slots (NOT 262144 —
    // that off-by-2x clobbered perm and crashed rounds 6/7).
    float* wsf = (float*)d_ws;
    __bf16*   hi     = (__bf16*)wsf;                       // [0, 524288)
    float*    sq     = wsf + 524288;                       // 8192
    unsigned* maxp   = (unsigned*)(wsf + 532480);          // 8192
    unsigned* minn   = (unsigned*)(wsf + 540672);          // 8192
    float*    sumcnt = wsf + 548864;                       // 4 (2 used)
    unsigned* start  = (unsigned*)(wsf + 548868);          // 1025 (pad to 1028)
    unsigned* offset = (unsigned*)(wsf + 549896);          // 1024
    int*      perm   = (int*)(wsf + 550920);               // 8192
    int*      slab   = (int*)(wsf + 559112);               // 8192 (16B-aligned)
    float*    out    = (float*)d_out;

    k_sort<<<dim3(1), dim3(1024), 0, stream>>>(labels, start, offset);
    k_scatter<<<dim3(BSZ / 256), dim3(256), 0, stream>>>(labels, offset, perm, slab);
    k_prep<<<dim3(BSZ / 4), dim3(256), 0, stream>>>(emb, perm, hi, sq, maxp, minn, sumcnt);
    k_mfma<<<dim3(BSZ / 128, NJ), dim3(256), 0, stream>>>(hi, slab, start, sq, maxp, minn);
    k_final<<<dim3(BSZ / 256), dim3(256), 0, stream>>>(maxp, minn, sq, sumcnt);
    k_out<<<dim3(1), dim3(64), 0, stream>>>(sumcnt, out);
}

// Round 9
// 51.421 us; speedup vs baseline: 1.0429x; 1.0429x over previous
//
#include <hip/hip_runtime.h>

#define BSZ 8192
#define DIM 128
#define NLAB 1024
#define MARGIN 0.3f
#define EPS 1e-8f
#define NJ 32              // j-splits
#define JCHUNK 256         // BSZ / NJ
#define NPH 8              // phases per block (32 cols each)

typedef __bf16 bf16x8 __attribute__((ext_vector_type(8)));
typedef float f32x4 __attribute__((ext_vector_type(4)));

#define AS1 __attribute__((address_space(1)))
#define AS3 __attribute__((address_space(3)))

// order-preserving float <-> uint key
__device__ __forceinline__ unsigned enc_ord(float f) {
    unsigned u = __float_as_uint(f);
    return (u & 0x80000000u) ? ~u : (u | 0x80000000u);
}
__device__ __forceinline__ float dec_ord(unsigned e) {
    unsigned u = (e & 0x80000000u) ? (e & 0x7FFFFFFFu) : ~e;
    return __uint_as_float(u);
}

template <int N>
__device__ __forceinline__ void waitv() {
    if constexpr (N == 4) asm volatile("s_waitcnt vmcnt(4)" ::: "memory");
    else if constexpr (N == 2) asm volatile("s_waitcnt vmcnt(2)" ::: "memory");
    else asm volatile("s_waitcnt vmcnt(0)" ::: "memory");
}

// ---- histogram + scan (1 block, 1024 thr) + one-time inits ----
__global__ __launch_bounds__(1024) void k_histscan(const int* __restrict__ labels,
                                                   unsigned* __restrict__ start,
                                                   unsigned* __restrict__ offset,
                                                   unsigned* __restrict__ ticket,
                                                   float* __restrict__ sumcnt) {
    __shared__ unsigned h[NLAB];
    const int tid = threadIdx.x;
    h[tid] = 0u;
    __syncthreads();
    const int4* l4 = (const int4*)labels;   // 2048 int4 = 8192 labels
    int4 a = l4[tid];
    int4 b = l4[tid + 1024];
    atomicAdd(&h[a.x], 1u); atomicAdd(&h[a.y], 1u);
    atomicAdd(&h[a.z], 1u); atomicAdd(&h[a.w], 1u);
    atomicAdd(&h[b.x], 1u); atomicAdd(&h[b.y], 1u);
    atomicAdd(&h[b.z], 1u); atomicAdd(&h[b.w], 1u);
    __syncthreads();
    // inclusive scan (Hillis-Steele)
    for (int d = 1; d < NLAB; d <<= 1) {
        unsigned w = (tid >= d) ? h[tid - d] : 0u;
        __syncthreads();
        h[tid] += w;
        __syncthreads();
    }
    start[tid + 1] = h[tid];
    offset[tid] = (tid > 0) ? h[tid - 1] : 0u;
    if (tid == 0) {
        start[0] = 0u;
        ticket[0] = 0u;
        sumcnt[0] = 0.0f;
        ((unsigned*)sumcnt)[1] = 0u;
    }
}

// fused scatter + gather + convert + norms + reduction init.
// One wave per row: lane 0 claims the sorted slot, all 64 lanes move the row.
__global__ __launch_bounds__(256) void k_gather(const float* __restrict__ emb,
                                                const int* __restrict__ labels,
                                                unsigned* __restrict__ offset,
                                                __bf16* __restrict__ hi,
                                                float* __restrict__ sq,
                                                int* __restrict__ slab,
                                                unsigned* __restrict__ maxp,
                                                unsigned* __restrict__ minn) {
    int row = blockIdx.x * 4 + (threadIdx.x >> 6);
    int lane = threadIdx.x & 63;
    int lab = labels[row];
    unsigned pos = 0;
    if (lane == 0) pos = atomicAdd(&offset[lab], 1u);
    pos = __shfl(pos, 0);
    float2 v = *(const float2*)&emb[(size_t)row * DIM + lane * 2];
    union { __bf16 b[2]; unsigned u; } p;
    p.b[0] = (__bf16)v.x;
    p.b[1] = (__bf16)v.y;
    ((unsigned*)hi)[pos * 64 + lane] = p.u;
    float s = v.x * v.x + v.y * v.y;
#pragma unroll
    for (int m = 32; m >= 1; m >>= 1) s += __shfl_xor(s, m);
    if (lane == 0) {
        sq[pos] = s;
        slab[pos] = lab;
        maxp[pos] = 0u;
        minn[pos] = 0xFFFFFFFFu;
    }
}

// 4 waves, 128 sorted anchor rows, 32-col phases, 4-deep LDS ring,
// depth-2 prefetch, counted vmcnt + raw s_barrier (no full drain in loop).
// Sorted labels => per-block positive band => ~94% negative-only phases.
__global__ __launch_bounds__(256, 4) void k_mfma(const __bf16* __restrict__ hi,
                                                 const int* __restrict__ slab,
                                                 const unsigned* __restrict__ startp,
                                                 const float* __restrict__ sq,
                                                 unsigned* __restrict__ maxp,
                                                 unsigned* __restrict__ minn) {
    __shared__ char Bst[4][8][1024];   // [ring buf][frag m][lane*16B]
    __shared__ float sqlds[JCHUNK];
    __shared__ int lablds[JCHUNK];

    const int tid = threadIdx.x;
    const int lane = tid & 63;
    const int wave = tid >> 6;
    const int lr = lane & 15;
    const int lq = lane >> 4;
    const int i0 = blockIdx.x * 128;
    const int it0 = i0 + wave * 32;
    const int it1 = it0 + 16;
    const int j0 = blockIdx.y * JCHUNK;
    const float INF = __uint_as_float(0x7F800000u);

    // positive band of this block's anchors (sorted rows => contiguous labels)
    const int lf = slab[i0];
    const int ll = slab[i0 + 127];
    const int blo = (int)startp[lf];
    const int bhi = (int)startp[ll + 1];
    unsigned mmask = 0;
#pragma unroll
    for (int tt = 0; tt < NPH; ++tt) {
        int c0 = j0 + tt * 32;
        if (bhi > c0 && blo < c0 + 32) mmask |= (1u << tt);
    }

    sqlds[tid] = sq[j0 + tid];
    lablds[tid] = slab[j0 + tid];

    // A fragments: 2 i-tiles x 4 K-frags, register-resident, pinned
    bf16x8 a0[4], a1[4];
    const __bf16* ap = hi + (size_t)(it0 + lr) * DIM + lq * 8;
#pragma unroll
    for (int f = 0; f < 4; ++f) {
        a0[f] = *(const bf16x8*)&ap[f * 32];
        a1[f] = *(const bf16x8*)&ap[16 * DIM + f * 32];
        asm volatile("" : "+v"(a0[f]));
        asm volatile("" : "+v"(a1[f]));
    }
    const int4 li0 = *(const int4*)&slab[it0 + lq * 4];
    const int4 li1 = *(const int4*)&slab[it1 + lq * 4];
    const int labi0[4] = {li0.x, li0.y, li0.z, li0.w};
    const int labi1[4] = {li1.x, li1.y, li1.z, li1.w};

    float mp0[4], mp1[4], mn0[4], mn1[4];
#pragma unroll
    for (int r = 0; r < 4; ++r) {
        mp0[r] = -INF; mp1[r] = -INF;
        mn0[r] = INF;  mn1[r] = INF;
    }

    // wave w stages frags m0=2w, m1=2w+1 (frag m: j-subtile m>>2, K-frag m&3)
    const int m0 = wave * 2, m1 = m0 + 1;
    const __bf16* bsA = hi + (size_t)(j0 + (m0 >> 2) * 16 + lr) * DIM + (m0 & 3) * 32 + lq * 8;
    const __bf16* bsB = hi + (size_t)(j0 + (m1 >> 2) * 16 + lr) * DIM + (m1 & 3) * 32 + lq * 8;
#define STAGE(t, buf)                                                              \
    do {                                                                           \
        __builtin_amdgcn_global_load_lds(                                          \
            (const AS1 void*)(bsA + (size_t)(t) * 32 * DIM),                       \
            (AS3 void*)&Bst[buf][m0][0], 16, 0, 0);                                \
        __builtin_amdgcn_global_load_lds(                                          \
            (const AS1 void*)(bsB + (size_t)(t) * 32 * DIM),                       \
            (AS3 void*)&Bst[buf][m1][0], 16, 0, 0);                                \
    } while (0)

    STAGE(0, 0);
    STAGE(1, 1);
    __syncthreads();   // full drain: bufs 0,1 resident; sqlds/lablds visible

#pragma unroll 1
    for (int t = 0; t < NPH; ++t) {
        if (t + 2 < NPH) STAGE(t + 2, (t + 2) & 3);
        if (t < NPH - 2) waitv<4>();         // retire phase-t loads (wave-local)
        else if (t == NPH - 2) waitv<2>();
        else waitv<0>();
        __builtin_amdgcn_s_barrier();        // all waves' phase-t frags resident
        __builtin_amdgcn_sched_barrier(0);   // pin ds_reads below the barrier

        const float sqj0 = sqlds[t * 32 + lr];
        const float sqj1 = sqlds[t * 32 + 16 + lr];

        const bf16x8* bp = (const bf16x8*)&Bst[t & 3][0][0];
        f32x4 acc00 = {0, 0, 0, 0}, acc01 = {0, 0, 0, 0};
        f32x4 acc10 = {0, 0, 0, 0}, acc11 = {0, 0, 0, 0};
#pragma unroll
        for (int f = 0; f < 4; ++f) {
            bf16x8 b0 = bp[f * 64 + lane];
            bf16x8 b1 = bp[(4 + f) * 64 + lane];
            acc00 = __builtin_amdgcn_mfma_f32_16x16x32_bf16(a0[f], b0, acc00, 0, 0, 0);
            acc10 = __builtin_amdgcn_mfma_f32_16x16x32_bf16(a1[f], b0, acc10, 0, 0, 0);
            acc01 = __builtin_amdgcn_mfma_f32_16x16x32_bf16(a0[f], b1, acc01, 0, 0, 0);
            acc11 = __builtin_amdgcn_mfma_f32_16x16x32_bf16(a1[f], b1, acc11, 0, 0, 0);
        }

        if (mmask & (1u << t)) {   // mixed phase: full label-aware epilogue
            const int labj0 = lablds[t * 32 + lr];
            const int labj1 = lablds[t * 32 + 16 + lr];
#pragma unroll
            for (int r = 0; r < 4; ++r) {
                float k00 = fmaf(-2.0f, acc00[r], sqj0);
                float k01 = fmaf(-2.0f, acc01[r], sqj1);
                float k10 = fmaf(-2.0f, acc10[r], sqj0);
                float k11 = fmaf(-2.0f, acc11[r], sqj1);
                bool s00 = (labj0 == labi0[r]);
                bool s01 = (labj1 == labi0[r]);
                bool s10 = (labj0 == labi1[r]);
                bool s11 = (labj1 == labi1[r]);
                mp0[r] = s00 ? fmaxf(mp0[r], k00) : mp0[r];
                mn0[r] = s00 ? mn0[r] : fminf(mn0[r], k00);
                mp0[r] = s01 ? fmaxf(mp0[r], k01) : mp0[r];
                mn0[r] = s01 ? mn0[r] : fminf(mn0[r], k01);
                mp1[r] = s10 ? fmaxf(mp1[r], k10) : mp1[r];
                mn1[r] = s10 ? mn1[r] : fminf(mn1[r], k10);
                mp1[r] = s11 ? fmaxf(mp1[r], k11) : mp1[r];
                mn1[r] = s11 ? mn1[r] : fminf(mn1[r], k11);
            }
        } else {   // pure-negative phase: fmaf + fmin tree only
#pragma unroll
            for (int r = 0; r < 4; ++r) {
                float k00 = fmaf(-2.0f, acc00[r], sqj0);
                float k01 = fmaf(-2.0f, acc01[r], sqj1);
                float k10 = fmaf(-2.0f, acc10[r], sqj0);
                float k11 = fmaf(-2.0f, acc11[r], sqj1);
                mn0[r] = fminf(fminf(mn0[r], k00), k01);
                mn1[r] = fminf(fminf(mn1[r], k10), k11);
            }
        }
    }
#undef STAGE

#pragma unroll
    for (int m = 1; m < 16; m <<= 1) {
#pragma unroll
        for (int r = 0; r < 4; ++r) {
            mp0[r] = fmaxf(mp0[r], __shfl_xor(mp0[r], m));
            mn0[r] = fminf(mn0[r], __shfl_xor(mn0[r], m));
            mp1[r] = fmaxf(mp1[r], __shfl_xor(mp1[r], m));
            mn1[r] = fminf(mn1[r], __shfl_xor(mn1[r], m));
        }
    }
    if (lr == 0) {
#pragma unroll
        for (int r = 0; r < 4; ++r) {
            atomicMax(&maxp[it0 + lq * 4 + r], enc_ord(mp0[r]));
            atomicMin(&minn[it0 + lq * 4 + r], enc_ord(mn0[r]));
            atomicMax(&maxp[it1 + lq * 4 + r], enc_ord(mp1[r]));
            atomicMin(&minn[it1 + lq * 4 + r], enc_ord(mn1[r]));
        }
    }
}

// per-anchor hinge + global sum; last block (ticket) computes the mean.
__global__ __launch_bounds__(256) void k_final(const unsigned* __restrict__ maxp,
                                               const unsigned* __restrict__ minn,
                                               const float* __restrict__ sq,
                                               float* __restrict__ sumcnt,
                                               unsigned* __restrict__ ticket,
                                               float* __restrict__ out) {
    int i = blockIdx.x * 256 + threadIdx.x;
    float mpd = dec_ord(maxp[i]);
    float mnd = dec_ord(minn[i]);
    float sqi = sq[i];
    bool valid = (mpd > -1e30f) && (mnd < 1e30f);
    float hp = sqrtf(fmaxf(sqi + mpd, 0.0f) + EPS);
    float hn = sqrtf(fmaxf(sqi + mnd, 0.0f) + EPS);
    float per = valid ? fmaxf(hp - hn + MARGIN, 0.0f) : 0.0f;
    unsigned cnt = valid ? 1u : 0u;
#pragma unroll
    for (int m = 32; m >= 1; m >>= 1) {
        per += __shfl_xor(per, m);
        cnt += __shfl_xor(cnt, m);
    }
    __shared__ float ssum[4];
    __shared__ unsigned scnt[4];
    int wid = threadIdx.x >> 6;
    if ((threadIdx.x & 63) == 0) { ssum[wid] = per; scnt[wid] = cnt; }
    __syncthreads();
    if (threadIdx.x == 0) {
        float s = ssum[0] + ssum[1] + ssum[2] + ssum[3];
        unsigned c = scnt[0] + scnt[1] + scnt[2] + scnt[3];
        atomicAdd(&sumcnt[0], s);
        atomicAdd((unsigned*)&sumcnt[1], c);
        __threadfence();
        unsigned done = atomicAdd(ticket, 1u);
        if (done == gridDim.x - 1) {
            // coherent re-reads via RMW(+0)
            float ts = atomicAdd(&sumcnt[0], 0.0f);
            unsigned tc = atomicAdd((unsigned*)&sumcnt[1], 0u);
            out[0] = ts / (float)(tc > 0u ? tc : 1u);
        }
    }
}

extern "C" void kernel_launch(void* const* d_in, const int* in_sizes, int n_in,
                              void* d_out, int out_size, void* d_ws, size_t ws_size,
                              hipStream_t stream) {
    const float* emb    = (const float*)d_in[0];
    const int*   labels = (const int*)d_in[1];

    // 4-byte-slot layout. hi = 8192*128 bf16 = 2 MB = 524288 slots.
    float* wsf = (float*)d_ws;
    __bf16*   hi     = (__bf16*)wsf;                       // [0, 524288)
    float*    sq     = wsf + 524288;                       // 8192
    unsigned* maxp   = (unsigned*)(wsf + 532480);          // 8192
    unsigned* minn   = (unsigned*)(wsf + 540672);          // 8192
    float*    sumcnt = wsf + 548864;                       // 4 (2 used)
    unsigned* start  = (unsigned*)(wsf + 548868);          // 1025 (pad to 1028)
    unsigned* offset = (unsigned*)(wsf + 549896);          // 1024
    unsigned* ticket = (unsigned*)(wsf + 550920);          // 1 (pad to 4)
    int*      slab   = (int*)(wsf + 550924);               // 8192 (16B-aligned)
    float*    out    = (float*)d_out;

    k_histscan<<<dim3(1), dim3(1024), 0, stream>>>(labels, start, offset, ticket, sumcnt);
    k_gather<<<dim3(BSZ / 4), dim3(256), 0, stream>>>(emb, labels, offset, hi, sq, slab, maxp, minn);
    k_mfma<<<dim3(BSZ / 128, NJ), dim3(256), 0, stream>>>(hi, slab, start, sq, maxp, minn);
    k_final<<<dim3(BSZ / 256), dim3(256), 0, stream>>>(maxp, minn, sq, sumcnt, ticket, out);
}